// Round 8
// baseline (302.836 us; speedup 1.0000x reference)
//
#include <hip/hip_runtime.h>
#include <hip/hip_bf16.h>

#define NOBJ 25

typedef short bf16x8 __attribute__((ext_vector_type(8)));
typedef short s16x4 __attribute__((ext_vector_type(4)));
typedef float f32x4 __attribute__((ext_vector_type(4)));

__device__ __forceinline__ short f2bf(float f) {
  __hip_bfloat16 b = __float2bfloat16(f);  // RTN
  return *reinterpret_cast<short*>(&b);
}
__device__ __forceinline__ float bf2f(short s) {
  unsigned u = ((unsigned)(unsigned short)s) << 16;
  return __uint_as_float(u);
}

// ===========================================================================
// DIAGNOSTIC ROUND: same algorithms as R7, split into 3 dispatches, each with
// an internal repeat loop so every dispatch exceeds the ~39us fill-kernel
// cutoff and gets a top-5 rocprof row. Repeats recompute/rewrite identical
// values (deterministic). dur_us is intentionally inflated ~10x.
// ===========================================================================

#define PREP_REP 32
#define CONV_REP 8
#define MLP_REP  16

// ---------------------------------------------------------------------------
// prep: MLP weights -> hi/lo bf16, fragment-linear. 264 blocks x 256 thr,
// 4 grid-stride iters exactly; repeated PREP_REP times.
// ---------------------------------------------------------------------------
__global__ __launch_bounds__(256) void prep_kernel(
    const float* __restrict__ w1, const float* __restrict__ w2,
    const float* __restrict__ w3, short* __restrict__ wfm) {
#pragma unroll 1
  for (int rep = 0; rep < PREP_REP; ++rep) {
    for (int j = blockIdx.x * 256 + threadIdx.x; j < 270336; j += 264 * 256) {
      const float* w; int term, f, nt;
      const bool isw3 = (j >= 262144);
      if (!isw3) {
        w = (j >> 17) ? w2 : w1;
        const int idx = j & 131071;
        term = idx >> 16; f = idx & 65535; nt = f >> 12;
      } else {
        w = w3;
        const int idx = j - 262144;  // 0..8191
        term = idx >> 12; f = idx & 4095; nt = 0;
      }
      const int ks = (f >> 9) & 7;
      const int l  = (f >> 3) & 63;
      const int jj = f & 7;
      const int col = nt * 16 + (l & 15);
      const int k   = ks * 32 + (l >> 4) * 8 + jj;
      const float v = (isw3 && col >= 10) ? 0.f : w[col * 256 + k];
      const short hi = f2bf(v);
      wfm[j] = (term == 0) ? hi : f2bf(v - bf2f(hi));
    }
  }
}

// ---------------------------------------------------------------------------
// conv: bf16 MFMA taps + wave-local pairwise pool (R5-style batched A/B).
// 512 blocks x 256 thr, 2 samples/block; body repeated CONV_REP times.
// ---------------------------------------------------------------------------
__global__ __launch_bounds__(256, 2) void conv_kernel(
    const float* __restrict__ x,    // (1024, 25*64)
    const float* __restrict__ cw0,  // (256, 64)
    const float* __restrict__ cw1,  // (256, 64)
    const float* __restrict__ cb,   // (256)
    float* __restrict__ h)          // (1024, 256)
{
  __shared__ short xs[2][32][72];        // 9216 B
  __shared__ float ab[4][2][NOBJ][68];   // 54400 B (per-wave scratch)

  const int t = threadIdx.x;
  const int lane = t & 63;
  const int wv = t >> 6;
  const int r = lane & 15;
  const int g = lane >> 4;
  const int n0 = blockIdx.x * 2;

  // one-time: W fragments for both taps (inline f32 -> bf16)
  bf16x8 Wf[2][4][2];  // [tap][ntile][kstep]
#pragma unroll
  for (int tap = 0; tap < 2; ++tap) {
    const float* wsrc = tap ? cw1 : cw0;
#pragma unroll
    for (int ntl = 0; ntl < 4; ++ntl)
#pragma unroll
      for (int ks = 0; ks < 2; ++ks) {
        const int ch = wv * 64 + ntl * 16 + r;
        const float* p = wsrc + ch * 64 + ks * 32 + g * 8;
        const float4 a = *reinterpret_cast<const float4*>(p);
        const float4 b = *reinterpret_cast<const float4*>(p + 4);
        bf16x8 fr;
        fr[0] = f2bf(a.x); fr[1] = f2bf(a.y); fr[2] = f2bf(a.z); fr[3] = f2bf(a.w);
        fr[4] = f2bf(b.x); fr[5] = f2bf(b.y); fr[6] = f2bf(b.z); fr[7] = f2bf(b.w);
        Wf[tap][ntl][ks] = fr;
      }
  }
  float cbv[4];
#pragma unroll
  for (int ntl = 0; ntl < 4; ++ntl) cbv[ntl] = cb[wv * 64 + ntl * 16 + r];

#pragma unroll 1
  for (int rep = 0; rep < CONV_REP; ++rep) {
    __syncthreads();  // protect xs against prior rep's readers
    for (int s = 0; s < 2; ++s) {
      const float4* xg = reinterpret_cast<const float4*>(x + (size_t)(n0 + s) * (NOBJ * 64));
      for (int i = t; i < 400; i += 256) {
        float4 v = xg[i];
        s16x4 p;
        p.x = f2bf(v.x); p.y = f2bf(v.y); p.z = f2bf(v.z); p.w = f2bf(v.w);
        *reinterpret_cast<s16x4*>(&xs[s][i >> 4][(i & 15) * 4]) = p;
      }
    }
    __syncthreads();

    for (int s = 0; s < 2; ++s) {
      bf16x8 Xf[2][2];  // [mtile][kstep]; rows 25..31 garbage, outputs unread
#pragma unroll
      for (int mt = 0; mt < 2; ++mt)
#pragma unroll
        for (int ks = 0; ks < 2; ++ks)
          Xf[mt][ks] = *reinterpret_cast<const bf16x8*>(&xs[s][mt * 16 + r][ks * 32 + g * 8]);

      f32x4 acc[2][2][4];  // [tap][mtile][ntile]
#pragma unroll
      for (int tap = 0; tap < 2; ++tap)
#pragma unroll
        for (int mt = 0; mt < 2; ++mt)
#pragma unroll
          for (int ntl = 0; ntl < 4; ++ntl) {
            f32x4 z = {0.f, 0.f, 0.f, 0.f};
            acc[tap][mt][ntl] = z;
          }

#pragma unroll
      for (int tap = 0; tap < 2; ++tap)
#pragma unroll
        for (int mt = 0; mt < 2; ++mt)
#pragma unroll
          for (int ntl = 0; ntl < 4; ++ntl)
#pragma unroll
            for (int ks = 0; ks < 2; ++ks)
              acc[tap][mt][ntl] = __builtin_amdgcn_mfma_f32_16x16x32_bf16(
                  Xf[mt][ks], Wf[tap][ntl][ks], acc[tap][mt][ntl], 0, 0, 0);

      // wave-local scatter (D: col=lane&15 -> channel, row=4g+q -> object)
#pragma unroll
      for (int tap = 0; tap < 2; ++tap)
#pragma unroll
        for (int mt = 0; mt < 2; ++mt)
#pragma unroll
          for (int ntl = 0; ntl < 4; ++ntl) {
            const int cl = ntl * 16 + r;
            const int row0 = mt * 16 + g * 4;
            const float badd = (tap == 0) ? cbv[ntl] : 0.f;
#pragma unroll
            for (int q = 0; q < 4; ++q)
              if (row0 + q < NOBJ) ab[wv][tap][row0 + q][cl] = acc[tap][mt][ntl][q] + badd;
          }
      // same-wave LDS RAW ordered by lgkmcnt; ab wave-private -> no barrier

      // pairwise: batched A/B register arrays (R5 form), static full unroll
      float A[NOBJ], Bv[NOBJ];
#pragma unroll
      for (int i = 0; i < NOBJ; ++i) { A[i] = ab[wv][0][i][lane]; Bv[i] = ab[wv][1][i][lane]; }
      float hacc = 0.f;
#pragma unroll
      for (int d = 1; d < NOBJ; ++d) {
        float sd = 0.f;
#pragma unroll
        for (int i = 0; i + d < NOBJ; ++i) sd += fmaxf(A[i] + Bv[i + d], 0.f);
        hacc = __builtin_fmaf(sd, 1.0f / (float)(NOBJ - d), hacc);
      }
      h[(size_t)(n0 + s) * 256 + t] = hacc * (1.0f / (float)(NOBJ - 1));
    }
  }
}

// ---------------------------------------------------------------------------
// mlp: fused 3-layer bf16-MFMA MLP, hi/lo split. 256 blocks x 512 thr,
// M=4 rows/block; body repeated MLP_REP times.
// ---------------------------------------------------------------------------
__global__ __launch_bounds__(512, 2) void mlp_mfma(
    const float* __restrict__ h,    // (1024, 256) f32
    const short* __restrict__ wf,   // fragment-linear hi/lo bf16 weights
    const float* __restrict__ b1, const float* __restrict__ b2,
    const float* __restrict__ b3,
    float* __restrict__ out)        // (1024, 10)
{
  __shared__ short H[2][2][4][272];  // [pingpong][hi/lo][row][k] 8704 B
  const int t = threadIdx.x, lane = t & 63, wv = t >> 6;
  const int r = lane & 15, g = lane >> 4;
  const int m0 = blockIdx.x * 4;

#pragma unroll 1
  for (int rep = 0; rep < MLP_REP; ++rep) {
    __syncthreads();  // protect H against prior rep's readers
    for (int i = t; i < 1024; i += 512) {
      const int row = i >> 8, k = i & 255;
      const float v = h[(size_t)(m0 + row) * 256 + k];
      const short hi = f2bf(v);
      H[0][0][row][k] = hi;
      H[0][1][row][k] = f2bf(v - bf2f(hi));
    }
    __syncthreads();

    int pp = 0;
    const float* bias[2] = {b1, b2};
#pragma unroll
    for (int L = 0; L < 2; ++L) {
      const short* wl = wf + L * 131072;

      bf16x8 ahi[8], alo[8];
#pragma unroll
      for (int ks = 0; ks < 8; ++ks) {
        const int ko = ks * 32 + g * 8;
        ahi[ks] = *reinterpret_cast<const bf16x8*>(&H[pp][0][r & 3][ko]);
        alo[ks] = *reinterpret_cast<const bf16x8*>(&H[pp][1][r & 3][ko]);
      }

      f32x4 acc[2];
#pragma unroll
      for (int ntl = 0; ntl < 2; ++ntl) {
        const float bv = bias[L][(wv * 2 + ntl) * 16 + r];
        f32x4 a = {bv, bv, bv, bv};
        acc[ntl] = a;
      }

      {  // hi-B bulk load, then 32 MFMAs (ahi*bhi + alo*bhi)
        bf16x8 bh[2][8];
#pragma unroll
        for (int ntl = 0; ntl < 2; ++ntl)
#pragma unroll
          for (int ks = 0; ks < 8; ++ks)
            bh[ntl][ks] = *reinterpret_cast<const bf16x8*>(
                wl + (((wv * 2 + ntl) * 8 + ks) << 9) + lane * 8);
#pragma unroll
        for (int ks = 0; ks < 8; ++ks)
#pragma unroll
          for (int ntl = 0; ntl < 2; ++ntl) {
            acc[ntl] = __builtin_amdgcn_mfma_f32_16x16x32_bf16(ahi[ks], bh[ntl][ks], acc[ntl], 0, 0, 0);
            acc[ntl] = __builtin_amdgcn_mfma_f32_16x16x32_bf16(alo[ks], bh[ntl][ks], acc[ntl], 0, 0, 0);
          }
      }
      {  // lo-B bulk load, then 16 MFMAs (ahi*blo)
        bf16x8 bl[2][8];
#pragma unroll
        for (int ntl = 0; ntl < 2; ++ntl)
#pragma unroll
          for (int ks = 0; ks < 8; ++ks)
            bl[ntl][ks] = *reinterpret_cast<const bf16x8*>(
                wl + 65536 + (((wv * 2 + ntl) * 8 + ks) << 9) + lane * 8);
#pragma unroll
        for (int ks = 0; ks < 8; ++ks)
#pragma unroll
          for (int ntl = 0; ntl < 2; ++ntl)
            acc[ntl] = __builtin_amdgcn_mfma_f32_16x16x32_bf16(ahi[ks], bl[ntl][ks], acc[ntl], 0, 0, 0);
      }

      if (g == 0) {  // D rows 0..3 = samples
#pragma unroll
        for (int ntl = 0; ntl < 2; ++ntl) {
          const int col = (wv * 2 + ntl) * 16 + r;
#pragma unroll
          for (int q = 0; q < 4; ++q) {
            const float v = fmaxf(acc[ntl][q], 0.f);
            const short hi = f2bf(v);
            H[pp ^ 1][0][q][col] = hi;
            H[pp ^ 1][1][q][col] = f2bf(v - bf2f(hi));
          }
        }
      }
      __syncthreads();
      pp ^= 1;
    }

    // layer 3: one 16x16 tile (cols 10..15 zero-padded), wave 0 only
    if (wv == 0) {
      const float bv = (r < 10) ? b3[r] : 0.f;
      f32x4 acc = {bv, bv, bv, bv};
      bf16x8 ahi[8], alo[8], bh[8], bl[8];
#pragma unroll
      for (int ks = 0; ks < 8; ++ks) {
        const int ko = ks * 32 + g * 8;
        ahi[ks] = *reinterpret_cast<const bf16x8*>(&H[pp][0][r & 3][ko]);
        alo[ks] = *reinterpret_cast<const bf16x8*>(&H[pp][1][r & 3][ko]);
        bh[ks] = *reinterpret_cast<const bf16x8*>(wf + 262144 + (ks << 9) + lane * 8);
        bl[ks] = *reinterpret_cast<const bf16x8*>(wf + 262144 + 4096 + (ks << 9) + lane * 8);
      }
#pragma unroll
      for (int ks = 0; ks < 8; ++ks) {
        acc = __builtin_amdgcn_mfma_f32_16x16x32_bf16(ahi[ks], bh[ks], acc, 0, 0, 0);
        acc = __builtin_amdgcn_mfma_f32_16x16x32_bf16(alo[ks], bh[ks], acc, 0, 0, 0);
        acc = __builtin_amdgcn_mfma_f32_16x16x32_bf16(ahi[ks], bl[ks], acc, 0, 0, 0);
      }
      if (g == 0 && r < 10) {
#pragma unroll
        for (int q = 0; q < 4; ++q)
          out[(size_t)(m0 + q) * 10 + r] = acc[q];
      }
    }
  }
}

extern "C" void kernel_launch(void* const* d_in, const int* in_sizes, int n_in,
                              void* d_out, int out_size, void* d_ws, size_t ws_size,
                              hipStream_t stream) {
  const float* x   = (const float*)d_in[0];
  const float* cw0 = (const float*)d_in[1];
  const float* cw1 = (const float*)d_in[2];
  const float* cb  = (const float*)d_in[3];
  const float* w1  = (const float*)d_in[4];
  const float* b1  = (const float*)d_in[5];
  const float* w2  = (const float*)d_in[6];
  const float* b2  = (const float*)d_in[7];
  const float* w3  = (const float*)d_in[8];
  const float* b3  = (const float*)d_in[9];
  float* out = (float*)d_out;

  float* h   = (float*)d_ws;                        // 1 MB: (1024,256) f32
  short* wfm = (short*)((char*)d_ws + (1 << 20));   // 540 KB: MLP frag weights

  prep_kernel<<<264, 256, 0, stream>>>(w1, w2, w3, wfm);
  conv_kernel<<<512, 256, 0, stream>>>(x, cw0, cw1, cb, h);
  mlp_mfma<<<256, 512, 0, stream>>>(h, wfm, b1, b2, b3, out);
}

// Round 9
// 35.351 us; speedup vs baseline: 8.5667x; 8.5667x over previous
//
#include <hip/hip_runtime.h>
#include <hip/hip_bf16.h>

#define NOBJ 25

typedef short bf16x8 __attribute__((ext_vector_type(8)));
typedef short s16x4 __attribute__((ext_vector_type(4)));
typedef float f32x4 __attribute__((ext_vector_type(4)));
typedef unsigned int uint;

__device__ __forceinline__ short f2bf(float f) {
  __hip_bfloat16 b = __float2bfloat16(f);  // RTN
  return *reinterpret_cast<short*>(&b);
}
__device__ __forceinline__ float bf2f(short s) {
  unsigned u = ((unsigned)(unsigned short)s) << 16;
  return __uint_as_float(u);
}
__device__ __forceinline__ uint packhl(float v) {
  const short hi = f2bf(v);
  const short lo = f2bf(v - bf2f(hi));
  return ((uint)(unsigned short)hi << 16) | (uint)(unsigned short)lo;
}

// ---------------------------------------------------------------------------
// prep: MLP weights -> hi/lo bf16, fragment-linear (unchanged layout).
// Layer L in {0,1} at L*131072: [term][nt][ks][lane][j];
// layer 3 at 262144: [term][ks][lane][j], cols>=10 zero-padded.
// value = w[(nt*16+(lane&15))*256 + ks*32 + (lane>>4)*8 + j]
// ---------------------------------------------------------------------------
__global__ __launch_bounds__(256) void prep_kernel(
    const float* __restrict__ w1, const float* __restrict__ w2,
    const float* __restrict__ w3, short* __restrict__ wfm) {
  for (int j = blockIdx.x * 256 + threadIdx.x; j < 270336; j += 264 * 256) {
    const float* w; int term, f, nt;
    const bool isw3 = (j >= 262144);
    if (!isw3) {
      w = (j >> 17) ? w2 : w1;
      const int idx = j & 131071;
      term = idx >> 16; f = idx & 65535; nt = f >> 12;
    } else {
      w = w3;
      const int idx = j - 262144;  // 0..8191
      term = idx >> 12; f = idx & 4095; nt = 0;
    }
    const int ks = (f >> 9) & 7;
    const int l  = (f >> 3) & 63;
    const int jj = f & 7;
    const int col = nt * 16 + (l & 15);
    const int k   = ks * 32 + (l >> 4) * 8 + jj;
    const float v = (isw3 && col >= 10) ? 0.f : w[col * 256 + k];
    const short hi = f2bf(v);
    wfm[j] = (term == 0) ? hi : f2bf(v - bf2f(hi));
  }
}

// ---------------------------------------------------------------------------
// conv: bf16 MFMA taps + wave-local pairwise pool (R7/R8 algorithm, verified).
// 512 blocks x 256 thr, 2 samples/block. Only change: h written PACKED hi|lo.
// ---------------------------------------------------------------------------
__global__ __launch_bounds__(256, 2) void conv_kernel(
    const float* __restrict__ x,    // (1024, 25*64)
    const float* __restrict__ cw0,  // (256, 64)
    const float* __restrict__ cw1,  // (256, 64)
    const float* __restrict__ cb,   // (256)
    uint* __restrict__ h0p)         // (1024, 256) packed hi|lo bf16
{
  __shared__ short xs[2][32][72];        // 9216 B
  __shared__ float ab[4][2][NOBJ][68];   // 54400 B (per-wave scratch)

  const int t = threadIdx.x;
  const int lane = t & 63;
  const int wv = t >> 6;
  const int r = lane & 15;
  const int g = lane >> 4;
  const int n0 = blockIdx.x * 2;

  bf16x8 Wf[2][4][2];  // [tap][ntile][kstep]
#pragma unroll
  for (int tap = 0; tap < 2; ++tap) {
    const float* wsrc = tap ? cw1 : cw0;
#pragma unroll
    for (int ntl = 0; ntl < 4; ++ntl)
#pragma unroll
      for (int ks = 0; ks < 2; ++ks) {
        const int ch = wv * 64 + ntl * 16 + r;
        const float* p = wsrc + ch * 64 + ks * 32 + g * 8;
        const float4 a = *reinterpret_cast<const float4*>(p);
        const float4 b = *reinterpret_cast<const float4*>(p + 4);
        bf16x8 fr;
        fr[0] = f2bf(a.x); fr[1] = f2bf(a.y); fr[2] = f2bf(a.z); fr[3] = f2bf(a.w);
        fr[4] = f2bf(b.x); fr[5] = f2bf(b.y); fr[6] = f2bf(b.z); fr[7] = f2bf(b.w);
        Wf[tap][ntl][ks] = fr;
      }
  }
  float cbv[4];
#pragma unroll
  for (int ntl = 0; ntl < 4; ++ntl) cbv[ntl] = cb[wv * 64 + ntl * 16 + r];

  for (int s = 0; s < 2; ++s) {
    const float4* xg = reinterpret_cast<const float4*>(x + (size_t)(n0 + s) * (NOBJ * 64));
    for (int i = t; i < 400; i += 256) {
      float4 v = xg[i];
      s16x4 p;
      p.x = f2bf(v.x); p.y = f2bf(v.y); p.z = f2bf(v.z); p.w = f2bf(v.w);
      *reinterpret_cast<s16x4*>(&xs[s][i >> 4][(i & 15) * 4]) = p;
    }
  }
  __syncthreads();

  for (int s = 0; s < 2; ++s) {
    bf16x8 Xf[2][2];  // rows 25..31 garbage, outputs unread
#pragma unroll
    for (int mt = 0; mt < 2; ++mt)
#pragma unroll
      for (int ks = 0; ks < 2; ++ks)
        Xf[mt][ks] = *reinterpret_cast<const bf16x8*>(&xs[s][mt * 16 + r][ks * 32 + g * 8]);

    f32x4 acc[2][2][4];  // [tap][mtile][ntile]
#pragma unroll
    for (int tap = 0; tap < 2; ++tap)
#pragma unroll
      for (int mt = 0; mt < 2; ++mt)
#pragma unroll
        for (int ntl = 0; ntl < 4; ++ntl) {
          f32x4 z = {0.f, 0.f, 0.f, 0.f};
          acc[tap][mt][ntl] = z;
        }

#pragma unroll
    for (int tap = 0; tap < 2; ++tap)
#pragma unroll
      for (int mt = 0; mt < 2; ++mt)
#pragma unroll
        for (int ntl = 0; ntl < 4; ++ntl)
#pragma unroll
          for (int ks = 0; ks < 2; ++ks)
            acc[tap][mt][ntl] = __builtin_amdgcn_mfma_f32_16x16x32_bf16(
                Xf[mt][ks], Wf[tap][ntl][ks], acc[tap][mt][ntl], 0, 0, 0);

#pragma unroll
    for (int tap = 0; tap < 2; ++tap)
#pragma unroll
      for (int mt = 0; mt < 2; ++mt)
#pragma unroll
        for (int ntl = 0; ntl < 4; ++ntl) {
          const int cl = ntl * 16 + r;
          const int row0 = mt * 16 + g * 4;
          const float badd = (tap == 0) ? cbv[ntl] : 0.f;
#pragma unroll
          for (int q = 0; q < 4; ++q)
            if (row0 + q < NOBJ) ab[wv][tap][row0 + q][cl] = acc[tap][mt][ntl][q] + badd;
        }
    // same-wave LDS RAW ordered by lgkmcnt; ab wave-private -> no barrier

    float A[NOBJ], Bv[NOBJ];
#pragma unroll
    for (int i = 0; i < NOBJ; ++i) { A[i] = ab[wv][0][i][lane]; Bv[i] = ab[wv][1][i][lane]; }
    float hacc = 0.f;
#pragma unroll
    for (int d = 1; d < NOBJ; ++d) {
      float sd = 0.f;
#pragma unroll
      for (int i = 0; i + d < NOBJ; ++i) sd += fmaxf(A[i] + Bv[i + d], 0.f);
      hacc = __builtin_fmaf(sd, 1.0f / (float)(NOBJ - d), hacc);
    }
    h0p[(size_t)(n0 + s) * 256 + t] = packhl(hacc * (1.0f / (float)(NOBJ - 1)));
  }
}

// ---------------------------------------------------------------------------
// mlp_mid: one layer, out = relu(in @ W^T + b), packed-hi|lo in and out.
// 256 blocks = 64 m-groups x 4 n-groups; M=16 rows, N=64 cols per block ->
// per-block weight stream 64KB (vs 528KB fused): total demand 16MB/layer.
// 256 thr (4 waves); wave wv -> nt = ng*4+wv. A staged hi/lo in LDS once;
// 16 B-frags bulk-loaded; 24 MFMAs; packed writeback (no 2nd barrier).
// ---------------------------------------------------------------------------
__global__ __launch_bounds__(256, 1) void mlp_mid(
    const uint* __restrict__ inp,   // (1024,256) packed
    const short* __restrict__ wl,   // this layer's frag-linear weights (lo @ +65536)
    const float* __restrict__ bias,
    uint* __restrict__ outp)        // (1024,256) packed
{
  __shared__ short Hs[2][16][272];  // [term][row][k] 17408 B
  const int t = threadIdx.x, lane = t & 63, wv = t >> 6;
  const int r = lane & 15, g = lane >> 4;
  const int m0 = (blockIdx.x >> 2) * 16;
  const int nt = (blockIdx.x & 3) * 4 + wv;

  const uint4* p4 = reinterpret_cast<const uint4*>(inp) + m0 * 64;
#pragma unroll
  for (int it = 0; it < 4; ++it) {
    const int idx = t + 256 * it;
    const uint4 u = p4[idx];
    const int row = idx >> 6, c = (idx & 63) * 4;
    s16x4 hi4, lo4;
    hi4.x = (short)(u.x >> 16); lo4.x = (short)(u.x & 0xffff);
    hi4.y = (short)(u.y >> 16); lo4.y = (short)(u.y & 0xffff);
    hi4.z = (short)(u.z >> 16); lo4.z = (short)(u.z & 0xffff);
    hi4.w = (short)(u.w >> 16); lo4.w = (short)(u.w & 0xffff);
    *reinterpret_cast<s16x4*>(&Hs[0][row][c]) = hi4;
    *reinterpret_cast<s16x4*>(&Hs[1][row][c]) = lo4;
  }
  __syncthreads();

  bf16x8 ahi[8], alo[8];
#pragma unroll
  for (int ks = 0; ks < 8; ++ks) {
    ahi[ks] = *reinterpret_cast<const bf16x8*>(&Hs[0][r][ks * 32 + g * 8]);
    alo[ks] = *reinterpret_cast<const bf16x8*>(&Hs[1][r][ks * 32 + g * 8]);
  }
  bf16x8 bh[8], bl[8];
#pragma unroll
  for (int ks = 0; ks < 8; ++ks) {
    bh[ks] = *reinterpret_cast<const bf16x8*>(wl + ((nt * 8 + ks) << 9) + lane * 8);
    bl[ks] = *reinterpret_cast<const bf16x8*>(wl + 65536 + ((nt * 8 + ks) << 9) + lane * 8);
  }
  const float bv = bias[nt * 16 + r];
  f32x4 acc = {bv, bv, bv, bv};
#pragma unroll
  for (int ks = 0; ks < 8; ++ks) {
    acc = __builtin_amdgcn_mfma_f32_16x16x32_bf16(ahi[ks], bh[ks], acc, 0, 0, 0);
    acc = __builtin_amdgcn_mfma_f32_16x16x32_bf16(alo[ks], bh[ks], acc, 0, 0, 0);
    acc = __builtin_amdgcn_mfma_f32_16x16x32_bf16(ahi[ks], bl[ks], acc, 0, 0, 0);
  }
  const int col = nt * 16 + r;
#pragma unroll
  for (int q = 0; q < 4; ++q)
    outp[(size_t)(m0 + 4 * g + q) * 256 + col] = packhl(fmaxf(acc[q], 0.f));
}

// ---------------------------------------------------------------------------
// mlp_last: out = in @ w3^T + b3 (N=10, zero-padded to 16). 64 blocks x 1
// wave, M=16. A-frags unpacked straight from the packed plane (no LDS).
// ---------------------------------------------------------------------------
__global__ __launch_bounds__(64, 1) void mlp_last(
    const uint* __restrict__ inp,   // (1024,256) packed
    const short* __restrict__ wf,   // wfm base (layer3 at +262144)
    const float* __restrict__ b3,
    float* __restrict__ out)        // (1024, 10)
{
  const int lane = threadIdx.x & 63;
  const int r = lane & 15, g = lane >> 4;
  const int m0 = blockIdx.x * 16;

  bf16x8 ahi[8], alo[8], bh[8], bl[8];
#pragma unroll
  for (int ks = 0; ks < 8; ++ks) {
    const uint* pe = inp + (size_t)(m0 + r) * 256 + ks * 32 + g * 8;
    const uint4 u0 = *reinterpret_cast<const uint4*>(pe);
    const uint4 u1 = *reinterpret_cast<const uint4*>(pe + 4);
    bf16x8 h8, l8;
    h8[0] = (short)(u0.x >> 16); l8[0] = (short)(u0.x & 0xffff);
    h8[1] = (short)(u0.y >> 16); l8[1] = (short)(u0.y & 0xffff);
    h8[2] = (short)(u0.z >> 16); l8[2] = (short)(u0.z & 0xffff);
    h8[3] = (short)(u0.w >> 16); l8[3] = (short)(u0.w & 0xffff);
    h8[4] = (short)(u1.x >> 16); l8[4] = (short)(u1.x & 0xffff);
    h8[5] = (short)(u1.y >> 16); l8[5] = (short)(u1.y & 0xffff);
    h8[6] = (short)(u1.z >> 16); l8[6] = (short)(u1.z & 0xffff);
    h8[7] = (short)(u1.w >> 16); l8[7] = (short)(u1.w & 0xffff);
    ahi[ks] = h8; alo[ks] = l8;
    bh[ks] = *reinterpret_cast<const bf16x8*>(wf + 262144 + (ks << 9) + lane * 8);
    bl[ks] = *reinterpret_cast<const bf16x8*>(wf + 262144 + 4096 + (ks << 9) + lane * 8);
  }
  const float bv = (r < 10) ? b3[r] : 0.f;
  f32x4 acc = {bv, bv, bv, bv};
#pragma unroll
  for (int ks = 0; ks < 8; ++ks) {
    acc = __builtin_amdgcn_mfma_f32_16x16x32_bf16(ahi[ks], bh[ks], acc, 0, 0, 0);
    acc = __builtin_amdgcn_mfma_f32_16x16x32_bf16(alo[ks], bh[ks], acc, 0, 0, 0);
    acc = __builtin_amdgcn_mfma_f32_16x16x32_bf16(ahi[ks], bl[ks], acc, 0, 0, 0);
  }
  if (r < 10) {
#pragma unroll
    for (int q = 0; q < 4; ++q)
      out[(size_t)(m0 + 4 * g + q) * 10 + r] = acc[q];
  }
}

extern "C" void kernel_launch(void* const* d_in, const int* in_sizes, int n_in,
                              void* d_out, int out_size, void* d_ws, size_t ws_size,
                              hipStream_t stream) {
  const float* x   = (const float*)d_in[0];
  const float* cw0 = (const float*)d_in[1];
  const float* cw1 = (const float*)d_in[2];
  const float* cb  = (const float*)d_in[3];
  const float* w1  = (const float*)d_in[4];
  const float* b1  = (const float*)d_in[5];
  const float* w2  = (const float*)d_in[6];
  const float* b2  = (const float*)d_in[7];
  const float* w3  = (const float*)d_in[8];
  const float* b3  = (const float*)d_in[9];
  float* out = (float*)d_out;

  uint* h0p = (uint*)d_ws;            // 1 MB packed
  uint* h1p = h0p + 262144;           // 1 MB packed
  uint* h2p = h1p + 262144;           // 1 MB packed
  short* wfm = (short*)(h2p + 262144);// 540 KB frag-linear weights

  prep_kernel<<<264, 256, 0, stream>>>(w1, w2, w3, wfm);
  conv_kernel<<<512, 256, 0, stream>>>(x, cw0, cw1, cb, h0p);
  mlp_mid<<<256, 256, 0, stream>>>(h0p, wfm, b1, h1p);
  mlp_mid<<<256, 256, 0, stream>>>(h1p, wfm + 131072, b2, h2p);
  mlp_last<<<64, 64, 0, stream>>>(h2p, wfm, b3, out);
}